// Round 1
// baseline (2958.554 us; speedup 1.0000x reference)
//
#include <hip/hip_runtime.h>
#include <hip/hip_bf16.h>

#define T_SEQ 2048
#define HDIM  4096
#define NQH   32
#define NKVH  8
#define HD_   128
#define FF_   14336

typedef short  s16x8 __attribute__((ext_vector_type(8)));
typedef short  s16x4 __attribute__((ext_vector_type(4)));
typedef float  f32x4 __attribute__((ext_vector_type(4)));

__device__ __forceinline__ short f2bf(float x) {
  __hip_bfloat16 h = __float2bfloat16(x);
  return *reinterpret_cast<short*>(&h);
}

__device__ __forceinline__ f32x4 mfma16(s16x8 a, s16x8 b, f32x4 c) {
  return __builtin_amdgcn_mfma_f32_16x16x32_bf16(a, b, c, 0, 0, 0);
}

__device__ __forceinline__ void gload_lds16(const void* g, void* l) {
  __builtin_amdgcn_global_load_lds(
      (__attribute__((address_space(1))) const void*)(unsigned long long)(g),
      (__attribute__((address_space(3))) void*)(unsigned long long)(l),
      16, 0, 0);
}

// ---------------------------------------------------------------------------
// Transpose + fp32->bf16 convert: in [R][C] f32 -> out [C][R] bf16. R,C % 64 == 0.
// ---------------------------------------------------------------------------
__global__ __launch_bounds__(256) void transpose_cvt_kernel(
    const float* __restrict__ in, short* __restrict__ out, int R, int C)
{
  __shared__ float tile[64][65];
  const int t = threadIdx.x;
  const int r0 = blockIdx.y * 64, c0 = blockIdx.x * 64;
  const int lr = t >> 4;            // 0..15
  const int lc = (t & 15) * 4;      // 0,4,...,60
  #pragma unroll
  for (int i = 0; i < 4; ++i) {
    int r = lr + i * 16;
    float4 v = *(const float4*)(in + (size_t)(r0 + r) * C + c0 + lc);
    tile[lc + 0][r] = v.x; tile[lc + 1][r] = v.y;
    tile[lc + 2][r] = v.z; tile[lc + 3][r] = v.w;
  }
  __syncthreads();
  const int oc = t >> 3;            // 0..31
  const int ch = (t & 7) * 8;       // 0,8,...,56
  #pragma unroll
  for (int i = 0; i < 2; ++i) {
    int c = oc + i * 32;
    s16x8 o;
    #pragma unroll
    for (int j = 0; j < 8; ++j) o[j] = f2bf(tile[c][ch + j]);
    *(s16x8*)(out + (size_t)(c0 + c) * R + r0 + ch) = o;
  }
}

// ---------------------------------------------------------------------------
// Fused (optional add) + RMSNorm. a [2048][4096] f32 (+b). Writes summed fp32
// (if hsout) and normalized bf16.
// ---------------------------------------------------------------------------
__global__ __launch_bounds__(256) void rmsnorm_kernel(
    const float* __restrict__ a, const float* __restrict__ b,
    const float* __restrict__ w, float* __restrict__ hsout,
    short* __restrict__ xout)
{
  const int row = blockIdx.x, t = threadIdx.x;
  const float* pa = a + (size_t)row * HDIM;
  float4 v[4];
  float ss = 0.f;
  #pragma unroll
  for (int i = 0; i < 4; ++i) {
    int c = t * 4 + i * 1024;
    v[i] = *(const float4*)(pa + c);
    if (b) {
      float4 vb = *(const float4*)(b + (size_t)row * HDIM + c);
      v[i].x += vb.x; v[i].y += vb.y; v[i].z += vb.z; v[i].w += vb.w;
    }
    ss += v[i].x * v[i].x + v[i].y * v[i].y + v[i].z * v[i].z + v[i].w * v[i].w;
  }
  #pragma unroll
  for (int d = 32; d; d >>= 1) ss += __shfl_down(ss, d, 64);
  __shared__ float red[4];
  if ((t & 63) == 0) red[t >> 6] = ss;
  __syncthreads();
  float tot = red[0] + red[1] + red[2] + red[3];
  float rms = rsqrtf(tot * (1.f / HDIM) + 1e-6f);
  #pragma unroll
  for (int i = 0; i < 4; ++i) {
    int c = t * 4 + i * 1024;
    if (hsout) *(float4*)(hsout + (size_t)row * HDIM + c) = v[i];
    float4 wv = *(const float4*)(w + c);
    s16x4 o;
    o[0] = f2bf(v[i].x * rms * wv.x); o[1] = f2bf(v[i].y * rms * wv.y);
    o[2] = f2bf(v[i].z * rms * wv.z); o[3] = f2bf(v[i].w * rms * wv.w);
    *(s16x4*)(xout + (size_t)row * HDIM + c) = o;
  }
}

// ---------------------------------------------------------------------------
// RoPE sin/cos table: [T][64] each.
// ---------------------------------------------------------------------------
__global__ __launch_bounds__(256) void rope_table_kernel(
    const int* __restrict__ pos, float* __restrict__ ct, float* __restrict__ st)
{
  int idx = blockIdx.x * 256 + threadIdx.x;   // T*64 entries
  int t = idx >> 6, i = idx & 63;
  float p = (float)pos[t];
  float inv = exp2f(-(float)i * (13.287712379549449f / 64.f)); // 10000^(-i/64)
  float f = p * inv;
  float sv, cv;
  sincosf(f, &sv, &cv);
  ct[idx] = cv; st[idx] = sv;
}

// ---------------------------------------------------------------------------
// Apply RoPE to q,k (f32 in), write bf16.
// ---------------------------------------------------------------------------
__global__ __launch_bounds__(256) void rope_kernel(
    const float* __restrict__ q, const float* __restrict__ k,
    const float* __restrict__ ct, const float* __restrict__ st,
    short* __restrict__ qb, short* __restrict__ kb)
{
  const int t = blockIdx.x, tid = threadIdx.x;
  const float* qr = q + (size_t)t * (NQH * HD_);
  const float* kr = k + (size_t)t * (NKVH * HD_);
  short* qo = qb + (size_t)t * (NQH * HD_);
  short* ko = kb + (size_t)t * (NKVH * HD_);
  for (int p = tid; p < NQH * 64; p += 256) {
    int hh = p >> 6, i = p & 63;
    float c = ct[t * 64 + i], s = st[t * 64 + i];
    float x1 = qr[hh * HD_ + i], x2 = qr[hh * HD_ + 64 + i];
    qo[hh * HD_ + i]      = f2bf(x1 * c - x2 * s);
    qo[hh * HD_ + 64 + i] = f2bf(x2 * c + x1 * s);
  }
  for (int p = tid; p < NKVH * 64; p += 256) {
    int hh = p >> 6, i = p & 63;
    float c = ct[t * 64 + i], s = st[t * 64 + i];
    float x1 = kr[hh * HD_ + i], x2 = kr[hh * HD_ + 64 + i];
    ko[hh * HD_ + i]      = f2bf(x1 * c - x2 * s);
    ko[hh * HD_ + 64 + i] = f2bf(x2 * c + x1 * s);
  }
}

// ---------------------------------------------------------------------------
// GEMM: C[M][N] = A[M][K](bf16) * Bt[N][K](bf16)^T with fused epilogues.
// m97 structure: 128x128 tile, BK=32, 4 waves (2x2), global_load_lds staging.
// mode 0: Cf = acc ; mode 1: Cf = acc + addv ; mode 2: Cb = bf16(acc*silu(gbuf))
// ---------------------------------------------------------------------------
__global__ __launch_bounds__(256) void gemm_bf16_kernel(
    const short* __restrict__ A, const short* __restrict__ Bt,
    int M, int N, int K, int mode,
    const float* __restrict__ addv, const float* __restrict__ gbuf,
    float* __restrict__ Cf, short* __restrict__ Cb)
{
  __shared__ short As[4096];   // [128 rows][32 k] bf16
  __shared__ short Bs[4096];   // [128 n-rows][32 k]
  const int tid = threadIdx.x;
  const int lane = tid & 63;
  const int w = tid >> 6;
  const int wr = w >> 1, wc = w & 1;
  const int m0 = blockIdx.y << 7, n0 = blockIdx.x << 7;
  const int lm = lane & 15, lg = lane >> 4;
  const int srow = lane >> 2, scol = (lane & 3) << 3;

  const short* ga = A  + (size_t)(m0 + w * 32 + srow) * K + scol;
  const short* gb = Bt + (size_t)(n0 + w * 32 + srow) * K + scol;
  short* lA = As + w * 32 * 32;
  short* lB = Bs + w * 32 * 32;

  const f32x4 z4 = {0.f, 0.f, 0.f, 0.f};
  f32x4 acc[4][4];
  #pragma unroll
  for (int i = 0; i < 4; ++i)
    #pragma unroll
    for (int j = 0; j < 4; ++j) acc[i][j] = z4;

  const int nk = K >> 5;
  for (int kt = 0; kt < nk; ++kt) {
    gload_lds16(ga,                lA);
    gload_lds16(ga + (size_t)16*K, lA + 512);
    gload_lds16(gb,                lB);
    gload_lds16(gb + (size_t)16*K, lB + 512);
    ga += 32; gb += 32;
    __syncthreads();
    s16x8 af[4], bfr[4];
    #pragma unroll
    for (int i = 0; i < 4; ++i) {
      af[i]  = *(const s16x8*)(As + ((wr * 64 + i * 16 + lm) << 5) + (lg << 3));
      bfr[i] = *(const s16x8*)(Bs + ((wc * 64 + i * 16 + lm) << 5) + (lg << 3));
    }
    #pragma unroll
    for (int mi = 0; mi < 4; ++mi)
      #pragma unroll
      for (int ni = 0; ni < 4; ++ni)
        acc[mi][ni] = mfma16(af[mi], bfr[ni], acc[mi][ni]);
    __syncthreads();
  }

  // Epilogue. C/D layout: col = lane&15, row = (lane>>4)*4 + reg.
  #pragma unroll
  for (int mi = 0; mi < 4; ++mi) {
    #pragma unroll
    for (int ni = 0; ni < 4; ++ni) {
      #pragma unroll
      for (int r = 0; r < 4; ++r) {
        int row = m0 + wr * 64 + mi * 16 + lg * 4 + r;
        int col = n0 + wc * 64 + ni * 16 + lm;
        size_t idx = (size_t)row * N + col;
        float v = acc[mi][ni][r];
        if (mode == 0) {
          Cf[idx] = v;
        } else if (mode == 1) {
          Cf[idx] = v + addv[idx];
        } else {
          float g = gbuf[idx];
          Cb[idx] = f2bf(v * g / (1.f + __expf(-g)));
        }
      }
    }
  }
}

// ---------------------------------------------------------------------------
// Flash attention, causal GQA. Qb [T][NQH*HD] bf16, Kb [T][NKVH*HD] bf16,
// Vt [NKVH*HD][T] bf16 (transposed). O [T][NQH*HD] bf16.
// 4 independent waves per block, 16 q-rows each, KV tile = 32.
// ---------------------------------------------------------------------------
__global__ __launch_bounds__(256) void attn_kernel(
    const short* __restrict__ Qb, const short* __restrict__ Kb,
    const short* __restrict__ Vt, short* __restrict__ O)
{
  __shared__ short P[4][16][32];   // per-wave P staging
  const int tid = threadIdx.x;
  const int lane = tid & 63, w = tid >> 6;
  const int lm = lane & 15, lg = lane >> 4;
  const int h = blockIdx.y, kvh = h >> 2;
  const int qw = blockIdx.x * 64 + w * 16;
  const float CEXP = 0.08838834764831845f * 1.4426950408889634f; // scale*log2e

  s16x8 qf[4];
  #pragma unroll
  for (int kc = 0; kc < 4; ++kc)
    qf[kc] = *(const s16x8*)(Qb + (size_t)(qw + lm) * (NQH * HD_) + h * HD_ + kc * 32 + lg * 8);

  const f32x4 z4 = {0.f, 0.f, 0.f, 0.f};
  f32x4 oacc[8];
  #pragma unroll
  for (int dg = 0; dg < 8; ++dg) oacc[dg] = z4;
  float m_[4], l_[4];
  #pragma unroll
  for (int r = 0; r < 4; ++r) { m_[r] = -INFINITY; l_[r] = 0.f; }

  const int ntiles = (qw + 16 + 31) >> 5;
  for (int kt = 0; kt < ntiles; ++kt) {
    const int kv0 = kt * 32;
    f32x4 s0 = z4, s1 = z4;
    const short* kb0 = Kb + (size_t)(kv0 + lm) * (NKVH * HD_) + kvh * HD_ + lg * 8;
    #pragma unroll
    for (int kc = 0; kc < 4; ++kc) {
      s16x8 k0 = *(const s16x8*)(kb0 + kc * 32);
      s16x8 k1 = *(const s16x8*)(kb0 + (size_t)16 * (NKVH * HD_) + kc * 32);
      s0 = mfma16(qf[kc], k0, s0);
      s1 = mfma16(qf[kc], k1, s1);
    }
    if (kv0 + 31 > qw) {   // diagonal tile: causal mask
      #pragma unroll
      for (int r = 0; r < 4; ++r) {
        int q = qw + lg * 4 + r;
        if (kv0 + lm > q)      s0[r] = -INFINITY;
        if (kv0 + 16 + lm > q) s1[r] = -INFINITY;
      }
    }
    #pragma unroll
    for (int r = 0; r < 4; ++r) {
      float mx = fmaxf(s0[r], s1[r]);
      mx = fmaxf(mx, __shfl_xor(mx, 1));
      mx = fmaxf(mx, __shfl_xor(mx, 2));
      mx = fmaxf(mx, __shfl_xor(mx, 4));
      mx = fmaxf(mx, __shfl_xor(mx, 8));
      float mn = fmaxf(m_[r], mx);
      float al = exp2f((m_[r] - mn) * CEXP);
      float p0 = exp2f((s0[r] - mn) * CEXP);
      float p1 = exp2f((s1[r] - mn) * CEXP);
      float ps = p0 + p1;
      ps += __shfl_xor(ps, 1);
      ps += __shfl_xor(ps, 2);
      ps += __shfl_xor(ps, 4);
      ps += __shfl_xor(ps, 8);
      l_[r] = l_[r] * al + ps;
      m_[r] = mn;
      P[w][lg * 4 + r][lm]      = f2bf(p0);
      P[w][lg * 4 + r][16 + lm] = f2bf(p1);
      #pragma unroll
      for (int dg = 0; dg < 8; ++dg) oacc[dg][r] *= al;
    }
    asm volatile("s_waitcnt lgkmcnt(0)" ::: "memory");
    s16x8 ap = *(const s16x8*)(&P[w][lm][lg * 8]);
    const short* vb0 = Vt + (size_t)(kvh * HD_ + lm) * T_SEQ + kv0 + lg * 8;
    #pragma unroll
    for (int dg = 0; dg < 8; ++dg) {
      s16x8 vf = *(const s16x8*)(vb0 + (size_t)dg * 16 * T_SEQ);
      oacc[dg] = mfma16(ap, vf, oacc[dg]);
    }
  }
  #pragma unroll
  for (int r = 0; r < 4; ++r) {
    float inv = 1.f / l_[r];
    int qrow = qw + lg * 4 + r;
    #pragma unroll
    for (int dg = 0; dg < 8; ++dg)
      O[(size_t)qrow * (NQH * HD_) + h * HD_ + dg * 16 + lm] = f2bf(oacc[dg][r] * inv);
  }
}

// ---------------------------------------------------------------------------
// Workspace layout (bytes). Weights persist; activation pool reused by g32.
// ---------------------------------------------------------------------------
static constexpr size_t O_WQT = 0;
static constexpr size_t O_WKT = O_WQT + (size_t)4096 * 4096 * 2;
static constexpr size_t O_WVT = O_WKT + (size_t)4096 * 1024 * 2;
static constexpr size_t O_WOT = O_WVT + (size_t)4096 * 1024 * 2;
static constexpr size_t O_WGT = O_WOT + (size_t)4096 * 4096 * 2;
static constexpr size_t O_WUT = O_WGT + (size_t)4096 * 14336 * 2;
static constexpr size_t O_WDT = O_WUT + (size_t)4096 * 14336 * 2;
static constexpr size_t O_POOL = O_WDT + (size_t)4096 * 14336 * 2;
static constexpr size_t O_HS  = O_POOL;
static constexpr size_t O_X1  = O_HS  + (size_t)2048 * 4096 * 4;
static constexpr size_t O_Q32 = O_X1  + (size_t)2048 * 4096 * 2;
static constexpr size_t O_K32 = O_Q32 + (size_t)2048 * 4096 * 4;
static constexpr size_t O_V32 = O_K32 + (size_t)2048 * 1024 * 4;
static constexpr size_t O_QB  = O_V32 + (size_t)2048 * 1024 * 4;
static constexpr size_t O_KB  = O_QB  + (size_t)2048 * 4096 * 2;
static constexpr size_t O_VT  = O_KB  + (size_t)2048 * 1024 * 2;
static constexpr size_t O_AT  = O_VT  + (size_t)2048 * 1024 * 2;
static constexpr size_t O_POOL_END = O_AT + (size_t)2048 * 4096 * 2;
static constexpr size_t O_G32 = O_POOL;            // reused after attention
static constexpr size_t O_X2  = O_POOL_END;
static constexpr size_t O_H16 = O_X2  + (size_t)2048 * 4096 * 2;
static constexpr size_t O_CT  = O_H16 + (size_t)2048 * 14336 * 2;
static constexpr size_t O_ST  = O_CT  + (size_t)2048 * 64 * 4;

extern "C" void kernel_launch(void* const* d_in, const int* in_sizes, int n_in,
                              void* d_out, int out_size, void* d_ws, size_t ws_size,
                              hipStream_t stream) {
  const int*   positions = (const int*)  d_in[0];
  const float* hidden    = (const float*)d_in[1];
  const float* residual  = (const float*)d_in[2];
  const float* w_q  = (const float*)d_in[3];
  const float* w_k  = (const float*)d_in[4];
  const float* w_v  = (const float*)d_in[5];
  const float* w_o  = (const float*)d_in[6];
  const float* w_g  = (const float*)d_in[7];
  const float* w_u  = (const float*)d_in[8];
  const float* w_d  = (const float*)d_in[9];
  const float* ln1  = (const float*)d_in[10];
  const float* ln2  = (const float*)d_in[11];

  float* out_x    = (float*)d_out;
  float* out_res2 = out_x + (size_t)T_SEQ * HDIM;

  char* ws = (char*)d_ws;
  short* wqT = (short*)(ws + O_WQT);
  short* wkT = (short*)(ws + O_WKT);
  short* wvT = (short*)(ws + O_WVT);
  short* woT = (short*)(ws + O_WOT);
  short* wgT = (short*)(ws + O_WGT);
  short* wuT = (short*)(ws + O_WUT);
  short* wdT = (short*)(ws + O_WDT);
  float* hs  = (float*)(ws + O_HS);
  short* x1  = (short*)(ws + O_X1);
  float* q32 = (float*)(ws + O_Q32);
  float* k32 = (float*)(ws + O_K32);
  float* v32 = (float*)(ws + O_V32);
  short* qb  = (short*)(ws + O_QB);
  short* kb  = (short*)(ws + O_KB);
  short* vt  = (short*)(ws + O_VT);
  short* at  = (short*)(ws + O_AT);
  float* g32 = (float*)(ws + O_G32);
  short* x2  = (short*)(ws + O_X2);
  short* h16 = (short*)(ws + O_H16);
  float* ct  = (float*)(ws + O_CT);
  float* st  = (float*)(ws + O_ST);

  dim3 blk(256);

  // Weight fp32 -> bf16 [N][K] transposes
  transpose_cvt_kernel<<<dim3(64, 64),   blk, 0, stream>>>(w_q, wqT, 4096, 4096);
  transpose_cvt_kernel<<<dim3(16, 64),   blk, 0, stream>>>(w_k, wkT, 4096, 1024);
  transpose_cvt_kernel<<<dim3(16, 64),   blk, 0, stream>>>(w_v, wvT, 4096, 1024);
  transpose_cvt_kernel<<<dim3(64, 64),   blk, 0, stream>>>(w_o, woT, 4096, 4096);
  transpose_cvt_kernel<<<dim3(224, 64),  blk, 0, stream>>>(w_g, wgT, 4096, 14336);
  transpose_cvt_kernel<<<dim3(224, 64),  blk, 0, stream>>>(w_u, wuT, 4096, 14336);
  transpose_cvt_kernel<<<dim3(64, 224),  blk, 0, stream>>>(w_d, wdT, 14336, 4096);

  rope_table_kernel<<<512, 256, 0, stream>>>(positions, ct, st);

  // hs = hidden + residual; x1 = rmsnorm(hs, ln1) in bf16
  rmsnorm_kernel<<<T_SEQ, 256, 0, stream>>>(hidden, residual, ln1, hs, x1);

  // QKV projections (fp32 out, pre-RoPE)
  gemm_bf16_kernel<<<dim3(32, 16), blk, 0, stream>>>(x1, wqT, T_SEQ, 4096, 4096, 0, nullptr, nullptr, q32, nullptr);
  gemm_bf16_kernel<<<dim3(8, 16),  blk, 0, stream>>>(x1, wkT, T_SEQ, 1024, 4096, 0, nullptr, nullptr, k32, nullptr);
  gemm_bf16_kernel<<<dim3(8, 16),  blk, 0, stream>>>(x1, wvT, T_SEQ, 1024, 4096, 0, nullptr, nullptr, v32, nullptr);

  rope_kernel<<<T_SEQ, 256, 0, stream>>>(q32, k32, ct, st, qb, kb);
  transpose_cvt_kernel<<<dim3(16, 32), blk, 0, stream>>>(v32, vt, 2048, 1024); // V -> [hd][T] bf16

  attn_kernel<<<dim3(T_SEQ / 64, NQH), blk, 0, stream>>>(qb, kb, vt, at);

  // O projection + residual -> res2 (second output)
  gemm_bf16_kernel<<<dim3(32, 16), blk, 0, stream>>>(at, woT, T_SEQ, 4096, 4096, 1, hs, nullptr, out_res2, nullptr);

  // x2 = rmsnorm(res2, ln2)
  rmsnorm_kernel<<<T_SEQ, 256, 0, stream>>>(out_res2, nullptr, ln2, nullptr, x2);

  // MLP: gate (fp32), up fused with silu(gate)*up -> bf16, down -> final output
  gemm_bf16_kernel<<<dim3(112, 16), blk, 0, stream>>>(x2, wgT, T_SEQ, FF_, 4096, 0, nullptr, nullptr, g32, nullptr);
  gemm_bf16_kernel<<<dim3(112, 16), blk, 0, stream>>>(x2, wuT, T_SEQ, FF_, 4096, 2, nullptr, g32, nullptr, h16);
  gemm_bf16_kernel<<<dim3(32, 16),  blk, 0, stream>>>(h16, wdT, T_SEQ, 4096, FF_, 0, nullptr, nullptr, out_x, nullptr);

  (void)in_sizes; (void)n_in; (void)out_size; (void)ws_size;
}